// Round 4
// baseline (504.973 us; speedup 1.0000x reference)
//
#include <hip/hip_runtime.h>
#include <hip/hip_bf16.h>

// BertSelfAttention (no mask). B=4, S=2048, H=1024, NH=16, HD=64. fp32 I/O.
// Round 10: qkv_gemm rewritten to the 256x256 8-wave fine-phase schedule
// (T2+T3+T4+T5): 4 phases per K-tile, each {stage 1 half-tile | barrier |
// ds_read subtile | lgkmcnt(0) | 16 MFMA | barrier}, counted vmcnt(2) once
// per K-tile (never drain-0 in loop). LDS 128KB double-buffered. attn/conv
// unchanged from round 9.
#define BB  4
#define SS  2048
#define HH  1024
#define NHH 16
#define HDD 64

typedef unsigned short u16;
typedef unsigned int   u32;
using bf16x8 = __attribute__((ext_vector_type(8))) short;   // 8 bf16 = 4 VGPRs
using f32x4  = __attribute__((ext_vector_type(4))) float;   // MFMA C/D 16x16
using f32x16 = __attribute__((ext_vector_type(16))) float;  // MFMA C/D 32x32
using u32x4  = __attribute__((ext_vector_type(4))) u32;

#define SBAR()   asm volatile("s_barrier" ::: "memory")
#define WAITV0() asm volatile("s_waitcnt vmcnt(0)" ::: "memory")
#define WAITV2() asm volatile("s_waitcnt vmcnt(2)" ::: "memory")
#define WAITV4() asm volatile("s_waitcnt vmcnt(4)" ::: "memory")
#define LGKM0()  asm volatile("s_waitcnt lgkmcnt(0)" ::: "memory")
#define SCHEDB() __builtin_amdgcn_sched_barrier(0)

// fp32 -> bf16 RNE.
__device__ __forceinline__ u16 f2b(float f) {
    union { float f; u32 u; } x; x.f = f;
    return (u16)((x.u + 0x7fffu + ((x.u >> 16) & 1u)) >> 16);
}

// async 16B global -> LDS (dest = wave-uniform base + lane*16).
__device__ __forceinline__ void gload16(const u16* g, u16* l) {
    __builtin_amdgcn_global_load_lds(
        (const __attribute__((address_space(1))) void*)g,
        (__attribute__((address_space(3))) void*)l, 16, 0, 0);
}

// ---------------------------------------------------------------------------
// conv: fused input conversion.
//   blocks [0,4096):      X fp32 -> bf16 straight copy (8 elems/thread)
//   blocks [4096,7168):   W[k][n] fp32 -> Wt[n][k] bf16 (32x32 transpose)
// ---------------------------------------------------------------------------
__global__ __launch_bounds__(256) void conv(
    const float* __restrict__ X,
    const float* __restrict__ Wq, const float* __restrict__ Wk,
    const float* __restrict__ Wv,
    u16* __restrict__ Xb, u16* __restrict__ Wt)
{
    const int bid = blockIdx.x;
    const int t = threadIdx.x;
    if (bid < 4096) {
        const int i = bid * 256 + t;
        float4 a = ((const float4*)X)[i * 2];
        float4 b = ((const float4*)X)[i * 2 + 1];
        ushort4 s0, s1;
        s0.x = f2b(a.x); s0.y = f2b(a.y); s0.z = f2b(a.z); s0.w = f2b(a.w);
        s1.x = f2b(b.x); s1.y = f2b(b.y); s1.z = f2b(b.z); s1.w = f2b(b.w);
        ((ushort4*)Xb)[i * 2] = s0;
        ((ushort4*)Xb)[i * 2 + 1] = s1;
        return;
    }
    const int idx = bid - 4096;
    const int z = idx >> 10, rem = idx & 1023;
    const int k0 = (rem >> 5) * 32, n0 = (rem & 31) * 32;
    const float* W = (z == 0) ? Wq : (z == 1) ? Wk : Wv;
    u16* out = Wt + (size_t)z * HH * HH;
    __shared__ float T[32][33];
    {
        const int kl = t >> 3, n4 = (t & 7) * 4;
        float4 v = *(const float4*)&W[(size_t)(k0 + kl) * HH + n0 + n4];
        T[n4 + 0][kl] = v.x; T[n4 + 1][kl] = v.y;
        T[n4 + 2][kl] = v.z; T[n4 + 3][kl] = v.w;
    }
    __syncthreads();
    {
        const int nl = t >> 3, k4 = (t & 7) * 4;
        ushort4 s;
        s.x = f2b(T[nl][k4 + 0]); s.y = f2b(T[nl][k4 + 1]);
        s.z = f2b(T[nl][k4 + 2]); s.w = f2b(T[nl][k4 + 3]);
        *(ushort4*)&out[(size_t)(n0 + nl) * HH + k0 + k4] = s;
    }
}

// ---------------------------------------------------------------------------
// qkv_gemm: 256x256 tile, BK=64, 512 threads = 8 waves (2m x 4n), per-wave
// output 128x64 (8 m-frags x 4 n-frags of 16x16x32 MFMA). LDS 128KB:
// double-buffered A[256x64] + B[256x64] bf16, XOR-swizzled, global_load_lds.
// Fine-phase K-loop: 4 phases/K-tile, quadrant (kc, n-half) per phase,
// stage one 16KB half-tile per phase into the other buffer, vmcnt(2) once
// per K-tile (phase 1 only; prefetch stays in flight across barriers).
// z<2 (Q,K): operands SWAPPED -> acc = D^T (regs step d) -> ushort4 stores
//            into [b,h,s,d]. Q pre-scaled by 0.125*log2(e).
// z=2 (V):   normal order -> ushort4 stores into V^T [b,h,d,s].
// ---------------------------------------------------------------------------
__global__ __launch_bounds__(512, 2) void qkv_gemm(
    const u16* __restrict__ Xb, const u16* __restrict__ Wtb,
    const float* __restrict__ bq, const float* __restrict__ bk,
    const float* __restrict__ bv,
    u16* __restrict__ Qw, u16* __restrict__ Kw, u16* __restrict__ Vw)
{
    const int z  = blockIdx.z;
    const float* bias = (z == 0) ? bq : (z == 1) ? bk : bv;
    const int m0 = blockIdx.x * 256, n0 = blockIdx.y * 256;

    __shared__ __align__(16) u16 As[2][256 * 64];   // 64 KB
    __shared__ __align__(16) u16 Bs[2][256 * 64];   // 64 KB

    const int t = threadIdx.x;
    const int w = t >> 6, lane = t & 63, lr = lane & 15, quad = lane >> 4;
    const int l3 = lane >> 3, c7 = lane & 7;
    const int cl = (c7 ^ l3) * 8;          // swizzled source column (u16)
    const int wm = w >> 2, wn = w & 3;     // 2 x 4 wave grid

    const u16* Wtz = Wtb + (size_t)z * HH * HH;

    // stage half-tile h of K-tile kt into buffer nb.
    // h=0: A rows 0..127, h=1: A rows 128..255, h=2: B rows 0..127, h=3: B hi.
    // 2 gloads (16 KB block-wide); wave w covers rows rbase..rbase+15.
    auto stage = [&](int h, int kt, int nb) {
        const int rbase = (h & 1) * 128 + w * 16;
        const int k0 = kt * 64;
        if (h < 2) {
            gload16(&Xb[(size_t)(m0 + rbase + l3) * HH + k0 + cl],
                    &As[nb][rbase * 64]);
            gload16(&Xb[(size_t)(m0 + rbase + 8 + l3) * HH + k0 + cl],
                    &As[nb][(rbase + 8) * 64]);
        } else {
            gload16(&Wtz[(size_t)(n0 + rbase + l3) * HH + k0 + cl],
                    &Bs[nb][rbase * 64]);
            gload16(&Wtz[(size_t)(n0 + rbase + 8 + l3) * HH + k0 + cl],
                    &Bs[nb][(rbase + 8) * 64]);
        }
    };

    f32x4 acc[8][4];
    #pragma unroll
    for (int i = 0; i < 8; i++)
        #pragma unroll
        for (int j = 0; j < 4; j++) acc[i][j] = f32x4{0.f, 0.f, 0.f, 0.f};

    // prologue: stage all 4 halves of K-tile 0 into buffer 0.
    stage(0, 0, 0); stage(1, 0, 0); stage(2, 0, 0); stage(3, 0, 0);

    bf16x8 af[8], bf[2];

    for (int kt = 0; kt < 16; kt++) {
        const int c = kt & 1, nb = c ^ 1;
        const bool pf = (kt < 15);

        // ---------- phase 1: quadrant (kc=0, n-half 0) ----------
        if (pf) { stage(0, kt + 1, nb); WAITV2(); } else { WAITV0(); }
        SBAR();
        #pragma unroll
        for (int mi = 0; mi < 8; mi++)
            af[mi] = *(const bf16x8*)&As[c][(wm * 128 + mi * 16 + lr) * 64
                                            + (quad ^ c7) * 8];
        #pragma unroll
        for (int j = 0; j < 2; j++)
            bf[j] = *(const bf16x8*)&Bs[c][(wn * 64 + j * 16 + lr) * 64
                                           + (quad ^ c7) * 8];
        LGKM0(); SCHEDB();
        __builtin_amdgcn_s_setprio(1);
        if (z != 2) {
            #pragma unroll
            for (int mi = 0; mi < 8; mi++)
                #pragma unroll
                for (int j = 0; j < 2; j++)
                    acc[mi][j] = __builtin_amdgcn_mfma_f32_16x16x32_bf16(
                        bf[j], af[mi], acc[mi][j], 0, 0, 0);
        } else {
            #pragma unroll
            for (int mi = 0; mi < 8; mi++)
                #pragma unroll
                for (int j = 0; j < 2; j++)
                    acc[mi][j] = __builtin_amdgcn_mfma_f32_16x16x32_bf16(
                        af[mi], bf[j], acc[mi][j], 0, 0, 0);
        }
        __builtin_amdgcn_s_setprio(0);
        SBAR();

        // ---------- phase 2: quadrant (kc=0, n-half 1) ----------
        if (pf) stage(1, kt + 1, nb);
        #pragma unroll
        for (int j = 0; j < 2; j++)
            bf[j] = *(const bf16x8*)&Bs[c][(wn * 64 + (2 + j) * 16 + lr) * 64
                                           + (quad ^ c7) * 8];
        SBAR();
        LGKM0(); SCHEDB();
        __builtin_amdgcn_s_setprio(1);
        if (z != 2) {
            #pragma unroll
            for (int mi = 0; mi < 8; mi++)
                #pragma unroll
                for (int j = 0; j < 2; j++)
                    acc[mi][2 + j] = __builtin_amdgcn_mfma_f32_16x16x32_bf16(
                        bf[j], af[mi], acc[mi][2 + j], 0, 0, 0);
        } else {
            #pragma unroll
            for (int mi = 0; mi < 8; mi++)
                #pragma unroll
                for (int j = 0; j < 2; j++)
                    acc[mi][2 + j] = __builtin_amdgcn_mfma_f32_16x16x32_bf16(
                        af[mi], bf[j], acc[mi][2 + j], 0, 0, 0);
        }
        __builtin_amdgcn_s_setprio(0);
        SBAR();

        // ---------- phase 3: quadrant (kc=1, n-half 0) ----------
        if (pf) stage(2, kt + 1, nb);
        #pragma unroll
        for (int mi = 0; mi < 8; mi++)
            af[mi] = *(const bf16x8*)&As[c][(wm * 128 + mi * 16 + lr) * 64
                                            + ((4 + quad) ^ c7) * 8];
        #pragma unroll
        for (int j = 0; j < 2; j++)
            bf[j] = *(const bf16x8*)&Bs[c][(wn * 64 + j * 16 + lr) * 64
                                           + ((4 + quad) ^ c7) * 8];
        SBAR();
        LGKM0(); SCHEDB();
        __builtin_amdgcn_s_setprio(1);
        if (z != 2) {
            #pragma unroll
            for (int mi = 0; mi < 8; mi++)
                #pragma unroll
                for (int j = 0; j < 2; j++)
                    acc[mi][j] = __builtin_amdgcn_mfma_f32_16x16x32_bf16(
                        bf[j], af[mi], acc[mi][j], 0, 0, 0);
        } else {
            #pragma unroll
            for (int mi = 0; mi < 8; mi++)
                #pragma unroll
                for (int j = 0; j < 2; j++)
                    acc[mi][j] = __builtin_amdgcn_mfma_f32_16x16x32_bf16(
                        af[mi], bf[j], acc[mi][j], 0, 0, 0);
        }
        __builtin_amdgcn_s_setprio(0);
        SBAR();

        // ---------- phase 4: quadrant (kc=1, n-half 1) ----------
        if (pf) stage(3, kt + 1, nb);
        #pragma unroll
        for (int j = 0; j < 2; j++)
            bf[j] = *(const bf16x8*)&Bs[c][(wn * 64 + (2 + j) * 16 + lr) * 64
                                           + ((4 + quad) ^ c7) * 8];
        SBAR();
        LGKM0(); SCHEDB();
        __builtin_amdgcn_s_setprio(1);
        if (z != 2) {
            #pragma unroll
            for (int mi = 0; mi < 8; mi++)
                #pragma unroll
                for (int j = 0; j < 2; j++)
                    acc[mi][2 + j] = __builtin_amdgcn_mfma_f32_16x16x32_bf16(
                        bf[j], af[mi], acc[mi][2 + j], 0, 0, 0);
        } else {
            #pragma unroll
            for (int mi = 0; mi < 8; mi++)
                #pragma unroll
                for (int j = 0; j < 2; j++)
                    acc[mi][2 + j] = __builtin_amdgcn_mfma_f32_16x16x32_bf16(
                        af[mi], bf[j], acc[mi][2 + j], 0, 0, 0);
        }
        __builtin_amdgcn_s_setprio(0);
        SBAR();
    }

    if (z != 2) {
        // acc = D^T: col(lane&15) = s-row, reg r = d-direction.
        u16* dst = (z == 0) ? Qw : Kw;
        const float cs = (z == 0) ? 0.18033688011112042f : 1.0f;
        #pragma unroll
        for (int mi = 0; mi < 8; mi++) {
            const int sg = m0 + wm * 128 + mi * 16 + lr;
            const int b = sg >> 11, s = sg & 2047;
            #pragma unroll
            for (int nf = 0; nf < 4; nf++) {
                const int nb2 = n0 + wn * 64 + nf * 16 + quad * 4;
                const int h = nb2 >> 6, d0 = nb2 & 63;
                float4 bb4 = *(const float4*)&bias[nb2];
                ushort4 vs;
                vs.x = f2b((acc[mi][nf][0] + bb4.x) * cs);
                vs.y = f2b((acc[mi][nf][1] + bb4.y) * cs);
                vs.z = f2b((acc[mi][nf][2] + bb4.z) * cs);
                vs.w = f2b((acc[mi][nf][3] + bb4.w) * cs);
                *(ushort4*)&dst[((size_t)(b * NHH + h) * SS + s) * HDD + d0] = vs;
            }
        }
    } else {
        // acc = D: col = d (n), reg r = s-direction -> V^T [b,h,d,s] stores.
        #pragma unroll
        for (int mi = 0; mi < 8; mi++)
            #pragma unroll
            for (int nf = 0; nf < 4; nf++) {
                const int mb = m0 + wm * 128 + mi * 16 + quad * 4;
                const int b = mb >> 11, s0 = mb & 2047;
                const int n = n0 + wn * 64 + nf * 16 + lr;
                const int h = n >> 6, d = n & 63;
                const float bv4 = bias[n];
                ushort4 vs;
                vs.x = f2b(acc[mi][nf][0] + bv4);
                vs.y = f2b(acc[mi][nf][1] + bv4);
                vs.z = f2b(acc[mi][nf][2] + bv4);
                vs.w = f2b(acc[mi][nf][3] + bv4);
                *(ushort4*)&Vw[((size_t)(b * NHH + h) * HDD + d) * SS + s0] = vs;
            }
    }
}

// ---------------------------------------------------------------------------
// attn: flash attention, M=0 softmax (p = exp2(s), Q pre-scaled).
// 256 threads = 4 waves; 64 q-rows/wave as two 32-row groups (A,B) sharing
// every K/V LDS read. 256 q/block, grid 512 (2 blocks/CU). 32x32x16 MFMA,
// swapped QK^T; P in registers (cvt_pk + permlane32_swap, T12).
// Counted vmcnt(4) + raw barriers; compute split QK0|QK1|pack0|PV01|pack1|PV23.
// (unchanged from round 9)
// ---------------------------------------------------------------------------
struct PU { union { u32x4 u; bf16x8 v; }; };

// pack one S-half (32 k-values in f32x16) -> 2 PV A-frags + lsum update.
__device__ __forceinline__ void packHalf(const f32x16& s, PU* pa, float& lsum) {
    float p[16];
    #pragma unroll
    for (int r = 0; r < 16; r++) p[r] = __builtin_amdgcn_exp2f(s[r]);
    lsum += ((((p[0] + p[1]) + (p[2] + p[3]))
            + ((p[4] + p[5]) + (p[6] + p[7])))
           + (((p[8] + p[9]) + (p[10] + p[11]))
            + ((p[12] + p[13]) + (p[14] + p[15]))));
    u32 x0, x1, x2, x3, y0, y1, y2, y3;
    asm("v_cvt_pk_bf16_f32 %0, %1, %2" : "=v"(x0) : "v"(p[0]),  "v"(p[1]));
    asm("v_cvt_pk_bf16_f32 %0, %1, %2" : "=v"(x1) : "v"(p[2]),  "v"(p[3]));
    asm("v_cvt_pk_bf16_f32 %0, %1, %2" : "=v"(y0) : "v"(p[4]),  "v"(p[5]));
    asm("v_cvt_pk_bf16_f32 %0, %1, %2" : "=v"(y1) : "v"(p[6]),  "v"(p[7]));
    asm("v_cvt_pk_bf16_f32 %0, %1, %2" : "=v"(x2) : "v"(p[8]),  "v"(p[9]));
    asm("v_cvt_pk_bf16_f32 %0, %1, %2" : "=v"(x3) : "v"(p[10]), "v"(p[11]));
    asm("v_cvt_pk_bf16_f32 %0, %1, %2" : "=v"(y2) : "v"(p[12]), "v"(p[13]));
    asm("v_cvt_pk_bf16_f32 %0, %1, %2" : "=v"(y3) : "v"(p[14]), "v"(p[15]));
    // swap hi-half(x) <-> lo-half(y): x' = frag reg{0,1}, y' = reg{2,3}
    asm("v_permlane32_swap_b32 %0, %1" : "+v"(x0), "+v"(y0));
    asm("v_permlane32_swap_b32 %0, %1" : "+v"(x1), "+v"(y1));
    asm("v_permlane32_swap_b32 %0, %1" : "+v"(x2), "+v"(y2));
    asm("v_permlane32_swap_b32 %0, %1" : "+v"(x3), "+v"(y3));
    pa[0].u = u32x4{x0, x1, y0, y1};   // k 0..15 of this half
    pa[1].u = u32x4{x2, x3, y2, y3};   // k 16..31 of this half
}

__global__ __launch_bounds__(256, 2) void attn(
    const u16* __restrict__ Qb, const u16* __restrict__ Kb,
    const u16* __restrict__ Vtb, float* __restrict__ Out)
{
    // hh = bid&63: all 8 q-blocks of a head land on XCD (hh&7).
    const int bid = blockIdx.x;
    const int hh = bid & 63, qt = bid >> 6;      // qt 0..7
    const int b = hh >> 4, h = hh & 15;
    const size_t hb = (size_t)hh * SS * HDD;

    __shared__ __align__(16) u16 Ks[2][64 * 64];
    __shared__ __align__(16) u16 Vs[2][64 * 64];

    const int t = threadIdx.x;
    const int w = t >> 6, lane = t & 63;
    const int q32 = lane & 31, hi = lane >> 5;
    const int l3 = lane >> 3, c7 = lane & 7;
    const int cl = (c7 ^ l3) * 8;          // swizzled source column (u16)

    // Q B-frags for both q-groups (col = q, k = d = ds*16 + hi*8 + j).
    bf16x8 qfA[4], qfB[4];
    {
        const size_t qrA = (size_t)(qt * 256 + w * 64 + q32);
        #pragma unroll
        for (int ds = 0; ds < 4; ds++) {
            qfA[ds] = *(const bf16x8*)&Qb[hb + qrA * HDD + ds * 16 + hi * 8];
            qfB[ds] = *(const bf16x8*)&Qb[hb + (qrA + 32) * HDD + ds * 16 + hi * 8];
        }
    }
    // Force the compiler's waitcnt for the Q loads to land HERE (pre-loop).
    asm volatile("" :: "v"(qfA[0]), "v"(qfA[1]), "v"(qfA[2]), "v"(qfA[3]),
                       "v"(qfB[0]), "v"(qfB[1]), "v"(qfB[2]), "v"(qfB[3]));

    // prologue: stage tile 0 into buffer 0 (4 gloads per wave).
    {
        const int r0 = w * 16 + l3, r1 = r0 + 8;
        gload16(&Kb [hb + (size_t)r0 * HDD + cl], &Ks[0][(w * 16) * 64]);
        gload16(&Kb [hb + (size_t)r1 * HDD + cl], &Ks[0][(w * 16 + 8) * 64]);
        gload16(&Vtb[hb + (size_t)r0 * SS + cl],  &Vs[0][(w * 16) * 64]);
        gload16(&Vtb[hb + (size_t)r1 * SS + cl],  &Vs[0][(w * 16 + 8) * 64]);
    }

    float lsA = 0.f, lsB = 0.f;
    f32x16 oA0 = {}, oA1 = {}, oB0 = {}, oB1 = {};

    for (int kt = 0; kt < SS / 64; kt++) {
        const int bb = kt & 1;
        if (kt + 1 < SS / 64) {   // issue prefetch, keep it in flight
            const int r0 = w * 16 + l3, r1 = r0 + 8;
            gload16(&Kb [hb + (size_t)((kt + 1) * 64 + r0) * HDD + cl],
                    &Ks[bb ^ 1][(w * 16) * 64]);
            gload16(&Kb [hb + (size_t)((kt + 1) * 64 + r1) * HDD + cl],
                    &Ks[bb ^ 1][(w * 16 + 8) * 64]);
            gload16(&Vtb[hb + (size_t)r0 * SS + (kt + 1) * 64 + cl],
                    &Vs[bb ^ 1][(w * 16) * 64]);
            gload16(&Vtb[hb + (size_t)r1 * SS + (kt + 1) * 64 + cl],
                    &Vs[bb ^ 1][(w * 16 + 8) * 64]);
            WAITV4();   // tile kt's 4 loads done; kt+1's 4 stay in flight
        } else {
            WAITV0();
        }
        SBAR();
        SCHEDB();

        // ---- QK half 0: K rows 0..31, both q-groups share kf.
        f32x16 sA0 = {}, sB0 = {};
        __builtin_amdgcn_s_setprio(1);
        #pragma unroll
        for (int ds = 0; ds < 4; ds++) {
            const int ph = ((ds * 2 + hi) ^ c7) * 8;
            bf16x8 kf = *(const bf16x8*)&Ks[bb][q32 * 64 + ph];
            sA0 = __builtin_amdgcn_mfma_f32_32x32x16_bf16(kf, qfA[ds], sA0, 0, 0, 0);
            sB0 = __builtin_amdgcn_mfma_f32_32x32x16_bf16(kf, qfB[ds], sB0, 0, 0, 0);
        }
        // ---- QK half 1: K rows 32..63.
        f32x16 sA1 = {}, sB1 = {};
        #pragma unroll
        for (int ds = 0; ds < 4; ds++) {
            const int ph = ((ds * 2 + hi) ^ c7) * 8;
            bf16x8 kf = *(const bf16x8*)&Ks[bb][(32 + q32) * 64 + ph];
            sA1 = __builtin_amdgcn_mfma_f32_32x32x16_bf16(kf, qfA[ds], sA1, 0, 0, 0);
            sB1 = __builtin_amdgcn_mfma_f32_32x32x16_bf16(kf, qfB[ds], sB1, 0, 0, 0);
        }
        __builtin_amdgcn_s_setprio(0);

        // ---- pack half 0 (overlaps half-1 MFMAs in the pipe).
        PU paA[4], paB[4];
        packHalf(sA0, &paA[0], lsA);
        packHalf(sB0, &paB[0], lsB);

        // ---- PV k-steps 0,1 (kv 0..31) — needs only pack half 0.
        __builtin_amdgcn_s_setprio(1);
        #pragma unroll
        for (int ks = 0; ks < 2; ks++) {
            const int ph = ((ks * 2 + hi) ^ c7) * 8;
            bf16x8 vf0 = *(const bf16x8*)&Vs[bb][q32 * 64 + ph];
            bf16x8 vf1 = *(const bf16x8*)&Vs[bb][(32 + q32) * 64 + ph];
            oA0 = __builtin_amdgcn_mfma_f32_32x32x16_bf16(paA[ks].v, vf0, oA0, 0, 0, 0);
            oA1 = __builtin_amdgcn_mfma_f32_32x32x16_bf16(paA[ks].v, vf1, oA1, 0, 0, 0);
            oB0 = __builtin_amdgcn_mfma_f32_32x32x16_bf16(paB[ks].v, vf0, oB0, 0, 0, 0);
            oB1 = __builtin_amdgcn_mfma_f32_32x32x16_bf16(paB[ks].v, vf1, oB1, 0, 0, 0);
        }
        __builtin_amdgcn_s_setprio(0);

        // ---- pack half 1 (overlaps PV01 MFMAs).
        packHalf(sA1, &paA[2], lsA);
        packHalf(sB1, &paB[2], lsB);

        // ---- PV k-steps 2,3 (kv 32..63).
        __builtin_amdgcn_s_setprio(1);
        #pragma unroll
        for (int ks = 2; ks < 4; ks++) {
            const int ph = ((ks * 2 + hi) ^ c7) * 8;
            bf16x8 vf0 = *(const bf16x8*)&Vs[bb][q32 * 64 + ph];
            bf16x8 vf1 = *(const bf16x8*)&Vs[bb][(32 + q32) * 64 + ph];
            oA0 = __builtin_amdgcn_mfma_f32_32x32x16_bf16(paA[ks].v, vf0, oA0, 0, 0, 0);
            oA1 = __builtin_amdgcn_mfma_f32_32x32x16_bf16(paA[ks].v, vf1, oA1, 0, 0, 0);
            oB0 = __builtin_amdgcn_mfma_f32_32x32x16_bf16(paB[ks].v, vf0, oB0, 0, 0, 0);
            oB1 = __builtin_amdgcn_mfma_f32_32x32x16_bf16(paB[ks].v, vf1, oB1, 0, 0, 0);
        }
        __builtin_amdgcn_s_setprio(0);

        SCHEDB();
        SBAR();   // all waves done reading buf bb (restaged at kt+2)
    }

    // ---- finalize l: q's row-sum is split across lanes q32 and q32+32.
    lsA += __shfl_xor(lsA, 32);
    lsB += __shfl_xor(lsB, 32);
    const float invA = 1.0f / lsA, invB = 1.0f / lsB;

    // oc rows are q = (r&3)+8*(r>>2)+4*hi; inv lives at lane q (lo half ok).
    #pragma unroll
    for (int r = 0; r < 16; r++) {
        const int cr = (r & 3) + 8 * (r >> 2) + 4 * hi;
        const float iA = __shfl(invA, cr);
        const float iB = __shfl(invB, cr);
        const int rqA = qt * 256 + w * 64 + cr;
        float* oA = &Out[((size_t)(b * SS + rqA)) * HH + h * HDD + q32];
        oA[0]  = oA0[r] * iA;
        oA[32] = oA1[r] * iA;
        float* oB = &Out[((size_t)(b * SS + rqA + 32)) * HH + h * HDD + q32];
        oB[0]  = oB0[r] * iB;
        oB[32] = oB1[r] * iB;
    }
}

// ---------------------------------------------------------------------------
extern "C" void kernel_launch(void* const* d_in, const int* in_sizes, int n_in,
                              void* d_out, int out_size, void* d_ws, size_t ws_size,
                              hipStream_t stream) {
    const float* X  = (const float*)d_in[0];
    const float* Wq = (const float*)d_in[1];
    const float* bq = (const float*)d_in[2];
    const float* Wk = (const float*)d_in[3];
    const float* bk = (const float*)d_in[4];
    const float* Wv = (const float*)d_in[5];
    const float* bv = (const float*)d_in[6];
    float* Out = (float*)d_out;

    const size_t elems = (size_t)BB * SS * HH;  // 8,388,608
    u16* Qw = (u16*)d_ws;                        // Q (pre-scaled) [b,h,s,d]
    u16* Kw = Qw + elems;                        // K [b,h,s,d]
    u16* Vw = Kw + elems;                        // V^T [b,h,d,s]
    // Xb/Wt scratch in d_out (23.1 MB < 33.5 MB; attn fully overwrites).
    u16* Xb = (u16*)d_out;
    u16* Wt = Xb + elems;

    conv<<<dim3(4096 + 3072), 256, 0, stream>>>(X, Wq, Wk, Wv, Xb, Wt);
    qkv_gemm<<<dim3(32, 4, 3), 512, 0, stream>>>(Xb, Wt, bq, bk, bv, Qw, Kw, Vw);
    attn<<<dim3(512), 256, 0, stream>>>(Qw, Kw, Vw, Out);
}

// Round 5
// 229.583 us; speedup vs baseline: 2.1995x; 2.1995x over previous
//
#include <hip/hip_runtime.h>
#include <hip/hip_bf16.h>

// BertSelfAttention (no mask). B=4, S=2048, H=1024, NH=16, HD=64. fp32 I/O.
// Round 11: qkv_gemm reverted to 128x128/2-phase (r9) + LDS-bounce epilogue:
// acc tiles bounce through wave-private LDS so ALL global stores are full
// 128B lines (r10 showed 459MB of HBM write traffic = 9.6x RMW amplification
// from stride-128B 8-byte stores). attn/conv unchanged from r9.
#define BB  4
#define SS  2048
#define HH  1024
#define NHH 16
#define HDD 64

typedef unsigned short u16;
typedef unsigned int   u32;
using bf16x8 = __attribute__((ext_vector_type(8))) short;   // 8 bf16 = 4 VGPRs
using f32x4  = __attribute__((ext_vector_type(4))) float;   // MFMA C/D 16x16
using f32x16 = __attribute__((ext_vector_type(16))) float;  // MFMA C/D 32x32
using u32x4  = __attribute__((ext_vector_type(4))) u32;

#define SBAR()   asm volatile("s_barrier" ::: "memory")
#define WAITV0() asm volatile("s_waitcnt vmcnt(0)" ::: "memory")
#define WAITV4() asm volatile("s_waitcnt vmcnt(4)" ::: "memory")
#define WAITV8() asm volatile("s_waitcnt vmcnt(8)" ::: "memory")
#define LGKM0()  asm volatile("s_waitcnt lgkmcnt(0)" ::: "memory")
#define SCHEDB() __builtin_amdgcn_sched_barrier(0)

// fp32 -> bf16 RNE.
__device__ __forceinline__ u16 f2b(float f) {
    union { float f; u32 u; } x; x.f = f;
    return (u16)((x.u + 0x7fffu + ((x.u >> 16) & 1u)) >> 16);
}

// async 16B global -> LDS (dest = wave-uniform base + lane*16).
__device__ __forceinline__ void gload16(const u16* g, u16* l) {
    __builtin_amdgcn_global_load_lds(
        (const __attribute__((address_space(1))) void*)g,
        (__attribute__((address_space(3))) void*)l, 16, 0, 0);
}

// ---------------------------------------------------------------------------
// conv: fused input conversion.
//   blocks [0,4096):      X fp32 -> bf16 straight copy (8 elems/thread)
//   blocks [4096,7168):   W[k][n] fp32 -> Wt[n][k] bf16 (32x32 transpose)
// ---------------------------------------------------------------------------
__global__ __launch_bounds__(256) void conv(
    const float* __restrict__ X,
    const float* __restrict__ Wq, const float* __restrict__ Wk,
    const float* __restrict__ Wv,
    u16* __restrict__ Xb, u16* __restrict__ Wt)
{
    const int bid = blockIdx.x;
    const int t = threadIdx.x;
    if (bid < 4096) {
        const int i = bid * 256 + t;
        float4 a = ((const float4*)X)[i * 2];
        float4 b = ((const float4*)X)[i * 2 + 1];
        ushort4 s0, s1;
        s0.x = f2b(a.x); s0.y = f2b(a.y); s0.z = f2b(a.z); s0.w = f2b(a.w);
        s1.x = f2b(b.x); s1.y = f2b(b.y); s1.z = f2b(b.z); s1.w = f2b(b.w);
        ((ushort4*)Xb)[i * 2] = s0;
        ((ushort4*)Xb)[i * 2 + 1] = s1;
        return;
    }
    const int idx = bid - 4096;
    const int z = idx >> 10, rem = idx & 1023;
    const int k0 = (rem >> 5) * 32, n0 = (rem & 31) * 32;
    const float* W = (z == 0) ? Wq : (z == 1) ? Wk : Wv;
    u16* out = Wt + (size_t)z * HH * HH;
    __shared__ float T[32][33];
    {
        const int kl = t >> 3, n4 = (t & 7) * 4;
        float4 v = *(const float4*)&W[(size_t)(k0 + kl) * HH + n0 + n4];
        T[n4 + 0][kl] = v.x; T[n4 + 1][kl] = v.y;
        T[n4 + 2][kl] = v.z; T[n4 + 3][kl] = v.w;
    }
    __syncthreads();
    {
        const int nl = t >> 3, k4 = (t & 7) * 4;
        ushort4 s;
        s.x = f2b(T[nl][k4 + 0]); s.y = f2b(T[nl][k4 + 1]);
        s.z = f2b(T[nl][k4 + 2]); s.w = f2b(T[nl][k4 + 3]);
        *(ushort4*)&out[(size_t)(n0 + nl) * HH + k0 + k4] = s;
    }
}

// ---------------------------------------------------------------------------
// qkv_gemm: 128x128 tile, BK=64, global_load_lds + XOR swizzle, 4 waves 2x2.
// Double-buffered LDS + counted vmcnt(8) + raw barriers (r9 structure).
// Epilogue (r11): per-wave 64x64 acc tile -> wave-private LDS bounce ->
// full-128B-line global stores (kills the 9.6x HBM write RMW amplification).
// z<2 (Q,K): operands SWAPPED -> acc = D^T (regs step d) -> [b,h,s,d] rows.
//            Q pre-scaled by 0.125*log2(e).
// z=2 (V):   normal order (regs step s) -> V^T [b,h,d,s] rows.
// ---------------------------------------------------------------------------
__global__ __launch_bounds__(256, 2) void qkv_gemm(
    const u16* __restrict__ Xb, const u16* __restrict__ Wtb,
    const float* __restrict__ bq, const float* __restrict__ bk,
    const float* __restrict__ bv,
    u16* __restrict__ Qw, u16* __restrict__ Kw, u16* __restrict__ Vw)
{
    const int z  = blockIdx.z;
    const float* bias = (z == 0) ? bq : (z == 1) ? bk : bv;
    const int m0 = blockIdx.x * 128, n0 = blockIdx.y * 128;

    __shared__ __align__(16) u16 Xs[2][128 * 64];
    __shared__ __align__(16) u16 Ws[2][128 * 64];

    const int t = threadIdx.x;
    const int w = t >> 6, lane = t & 63, lr = lane & 15, quad = lane >> 4;
    const int l3 = lane >> 3, c7 = lane & 7;
    const int cl = (c7 ^ l3) * 8;          // swizzled source column (u16)
    const int wm = w >> 1, wn = w & 1;

    const u16* Wtz = Wtb + (size_t)z * HH * HH;

    f32x4 acc[4][4];
    #pragma unroll
    for (int i = 0; i < 4; i++)
        #pragma unroll
        for (int j = 0; j < 4; j++) acc[i][j] = f32x4{0.f, 0.f, 0.f, 0.f};

    // prologue: stage tile 0 into buffer 0 (8 gloads per wave).
    #pragma unroll
    for (int e = 0; e < 4; e++) {
        const int r = w * 32 + e * 8 + l3;
        gload16(&Xb [(size_t)(m0 + r) * HH + cl], &Xs[0][(w * 32 + e * 8) * 64]);
        gload16(&Wtz[(size_t)(n0 + r) * HH + cl], &Ws[0][(w * 32 + e * 8) * 64]);
    }

    for (int kt = 0; kt < 16; kt++) {
        const int cur = kt & 1;
        if (kt < 15) {
            const int k0 = (kt + 1) * 64;
            #pragma unroll
            for (int e = 0; e < 4; e++) {
                const int r = w * 32 + e * 8 + l3;
                gload16(&Xb [(size_t)(m0 + r) * HH + k0 + cl],
                        &Xs[cur ^ 1][(w * 32 + e * 8) * 64]);
                gload16(&Wtz[(size_t)(n0 + r) * HH + k0 + cl],
                        &Ws[cur ^ 1][(w * 32 + e * 8) * 64]);
            }
            WAITV8();     // tile kt's 8 loads done; kt+1's 8 stay in flight
        } else {
            WAITV0();
        }
        SBAR();
        SCHEDB();

        #pragma unroll
        for (int kc = 0; kc < 2; kc++) {
            bf16x8 af[4], bfr[4];
            const int ph = ((kc * 4 + quad) ^ c7) * 8;
            #pragma unroll
            for (int mi = 0; mi < 4; mi++)
                af[mi] = *(const bf16x8*)&Xs[cur][(wm * 64 + mi * 16 + lr) * 64 + ph];
            #pragma unroll
            for (int ni = 0; ni < 4; ni++)
                bfr[ni] = *(const bf16x8*)&Ws[cur][(wn * 64 + ni * 16 + lr) * 64 + ph];
            if (z != 2) {   // swapped: acc[mi][ni] = (W.X^T) tile = D^T
                #pragma unroll
                for (int mi = 0; mi < 4; mi++)
                    #pragma unroll
                    for (int ni = 0; ni < 4; ni++)
                        acc[mi][ni] = __builtin_amdgcn_mfma_f32_16x16x32_bf16(
                            bfr[ni], af[mi], acc[mi][ni], 0, 0, 0);
            } else {
                #pragma unroll
                for (int mi = 0; mi < 4; mi++)
                    #pragma unroll
                    for (int ni = 0; ni < 4; ni++)
                        acc[mi][ni] = __builtin_amdgcn_mfma_f32_16x16x32_bf16(
                            af[mi], bfr[ni], acc[mi][ni], 0, 0, 0);
            }
        }
        SCHEDB();
        SBAR();           // all waves done reading buf cur (reused at kt+2)
    }

    // ---- epilogue: LDS bounce -> full-line stores.
    // Wave-private 8KB region in buffer-0 LDS (last K-tile used buffer 1;
    // my wave's buffer-0 reads finished at kt=14's end-barrier). XOR swizzle
    // byte ^= (row&7)<<4 keeps 8B/16B alignment, breaks bank collisions.
    u16* eb = (w < 2 ? &Xs[0][0] : &Ws[0][0]) + (w & 1) * 4096;

    if (z != 2) {
        // acc = D^T: lr = local s, (ni,quad,reg) = d. Dump as [s][d] 64x64.
        const float cs = (z == 0) ? 0.18033688011112042f : 1.0f;
        #pragma unroll
        for (int mi = 0; mi < 4; mi++) {
            const int rr = mi * 16 + lr;
            #pragma unroll
            for (int ni = 0; ni < 4; ni++) {
                const int nb = n0 + wn * 64 + ni * 16 + quad * 4;
                float4 bb4 = *(const float4*)&bias[nb];
                ushort4 vs;
                vs.x = f2b((acc[mi][ni][0] + bb4.x) * cs);
                vs.y = f2b((acc[mi][ni][1] + bb4.y) * cs);
                vs.z = f2b((acc[mi][ni][2] + bb4.z) * cs);
                vs.w = f2b((acc[mi][ni][3] + bb4.w) * cs);
                const int cbyte = (ni * 16 + quad * 4) * 2;
                *(ushort4*)((char*)eb + rr * 128 + (cbyte ^ ((rr & 7) << 4))) = vs;
            }
        }
    } else {
        // acc = D: lr = local d, (mi,quad,reg) = s. Dump as [d][s] 64x64.
        #pragma unroll
        for (int mi = 0; mi < 4; mi++) {
            #pragma unroll
            for (int ni = 0; ni < 4; ni++) {
                const int n = n0 + wn * 64 + ni * 16 + lr;
                const float bv4 = bias[n];
                ushort4 vs;
                vs.x = f2b(acc[mi][ni][0] + bv4);
                vs.y = f2b(acc[mi][ni][1] + bv4);
                vs.z = f2b(acc[mi][ni][2] + bv4);
                vs.w = f2b(acc[mi][ni][3] + bv4);
                const int rr = ni * 16 + lr;
                const int cbyte = (mi * 16 + quad * 4) * 2;
                *(ushort4*)((char*)eb + rr * 128 + (cbyte ^ ((rr & 7) << 4))) = vs;
            }
        }
    }
    LGKM0();
    SCHEDB();

    // read back rows; 8 lanes x 16B = one full 128B output line per row.
    {
        const int rg = lane >> 3;                 // row-in-group 0..7
        const int cb = (lane & 7) * 16;           // byte col 0..112
        const int h = (n0 + wn * 64) >> 6;        // head (64-aligned n-chunk)
        if (z != 2) {
            u16* dst = (z == 0) ? Qw : Kw;
            #pragma unroll
            for (int p = 0; p < 8; p++) {
                const int r2 = p * 8 + rg;        // local s
                bf16x8 rowv = *(const bf16x8*)
                    ((char*)eb + r2 * 128 + (cb ^ ((r2 & 7) << 4)));
                const int sg = m0 + wm * 64 + r2;
                const int b = sg >> 11, s = sg & 2047;
                *(bf16x8*)&dst[((size_t)(b * NHH + h) * SS + s) * HDD + (cb >> 1)]
                    = rowv;
            }
        } else {
            const int mb = m0 + wm * 64;
            const int b = mb >> 11, s0 = mb & 2047;
            #pragma unroll
            for (int p = 0; p < 8; p++) {
                const int r2 = p * 8 + rg;        // local d
                bf16x8 rowv = *(const bf16x8*)
                    ((char*)eb + r2 * 128 + (cb ^ ((r2 & 7) << 4)));
                *(bf16x8*)&Vw[((size_t)(b * NHH + h) * HDD + r2) * SS + s0 + (cb >> 1)]
                    = rowv;
            }
        }
    }
}

// ---------------------------------------------------------------------------
// attn: flash attention, M=0 softmax (p = exp2(s), Q pre-scaled).
// 256 threads = 4 waves; 64 q-rows/wave as two 32-row groups (A,B) sharing
// every K/V LDS read. 256 q/block, grid 512 (2 blocks/CU). 32x32x16 MFMA,
// swapped QK^T; P in registers (cvt_pk + permlane32_swap, T12).
// Counted vmcnt(4) + raw barriers; compute split QK0|QK1|pack0|PV01|pack1|PV23.
// (unchanged from round 9)
// ---------------------------------------------------------------------------
struct PU { union { u32x4 u; bf16x8 v; }; };

// pack one S-half (32 k-values in f32x16) -> 2 PV A-frags + lsum update.
__device__ __forceinline__ void packHalf(const f32x16& s, PU* pa, float& lsum) {
    float p[16];
    #pragma unroll
    for (int r = 0; r < 16; r++) p[r] = __builtin_amdgcn_exp2f(s[r]);
    lsum += ((((p[0] + p[1]) + (p[2] + p[3]))
            + ((p[4] + p[5]) + (p[6] + p[7])))
           + (((p[8] + p[9]) + (p[10] + p[11]))
            + ((p[12] + p[13]) + (p[14] + p[15]))));
    u32 x0, x1, x2, x3, y0, y1, y2, y3;
    asm("v_cvt_pk_bf16_f32 %0, %1, %2" : "=v"(x0) : "v"(p[0]),  "v"(p[1]));
    asm("v_cvt_pk_bf16_f32 %0, %1, %2" : "=v"(x1) : "v"(p[2]),  "v"(p[3]));
    asm("v_cvt_pk_bf16_f32 %0, %1, %2" : "=v"(y0) : "v"(p[4]),  "v"(p[5]));
    asm("v_cvt_pk_bf16_f32 %0, %1, %2" : "=v"(y1) : "v"(p[6]),  "v"(p[7]));
    asm("v_cvt_pk_bf16_f32 %0, %1, %2" : "=v"(x2) : "v"(p[8]),  "v"(p[9]));
    asm("v_cvt_pk_bf16_f32 %0, %1, %2" : "=v"(x3) : "v"(p[10]), "v"(p[11]));
    asm("v_cvt_pk_bf16_f32 %0, %1, %2" : "=v"(y2) : "v"(p[12]), "v"(p[13]));
    asm("v_cvt_pk_bf16_f32 %0, %1, %2" : "=v"(y3) : "v"(p[14]), "v"(p[15]));
    // swap hi-half(x) <-> lo-half(y): x' = frag reg{0,1}, y' = reg{2,3}
    asm("v_permlane32_swap_b32 %0, %1" : "+v"(x0), "+v"(y0));
    asm("v_permlane32_swap_b32 %0, %1" : "+v"(x1), "+v"(y1));
    asm("v_permlane32_swap_b32 %0, %1" : "+v"(x2), "+v"(y2));
    asm("v_permlane32_swap_b32 %0, %1" : "+v"(x3), "+v"(y3));
    pa[0].u = u32x4{x0, x1, y0, y1};   // k 0..15 of this half
    pa[1].u = u32x4{x2, x3, y2, y3};   // k 16..31 of this half
}

__global__ __launch_bounds__(256, 2) void attn(
    const u16* __restrict__ Qb, const u16* __restrict__ Kb,
    const u16* __restrict__ Vtb, float* __restrict__ Out)
{
    // hh = bid&63: all 8 q-blocks of a head land on XCD (hh&7).
    const int bid = blockIdx.x;
    const int hh = bid & 63, qt = bid >> 6;      // qt 0..7
    const int b = hh >> 4, h = hh & 15;
    const size_t hb = (size_t)hh * SS * HDD;

    __shared__ __align__(16) u16 Ks[2][64 * 64];
    __shared__ __align__(16) u16 Vs[2][64 * 64];

    const int t = threadIdx.x;
    const int w = t >> 6, lane = t & 63;
    const int q32 = lane & 31, hi = lane >> 5;
    const int l3 = lane >> 3, c7 = lane & 7;
    const int cl = (c7 ^ l3) * 8;          // swizzled source column (u16)

    // Q B-frags for both q-groups (col = q, k = d = ds*16 + hi*8 + j).
    bf16x8 qfA[4], qfB[4];
    {
        const size_t qrA = (size_t)(qt * 256 + w * 64 + q32);
        #pragma unroll
        for (int ds = 0; ds < 4; ds++) {
            qfA[ds] = *(const bf16x8*)&Qb[hb + qrA * HDD + ds * 16 + hi * 8];
            qfB[ds] = *(const bf16x8*)&Qb[hb + (qrA + 32) * HDD + ds * 16 + hi * 8];
        }
    }
    // Force the compiler's waitcnt for the Q loads to land HERE (pre-loop).
    asm volatile("" :: "v"(qfA[0]), "v"(qfA[1]), "v"(qfA[2]), "v"(qfA[3]),
                       "v"(qfB[0]), "v"(qfB[1]), "v"(qfB[2]), "v"(qfB[3]));

    // prologue: stage tile 0 into buffer 0 (4 gloads per wave).
    {
        const int r0 = w * 16 + l3, r1 = r0 + 8;
        gload16(&Kb [hb + (size_t)r0 * HDD + cl], &Ks[0][(w * 16) * 64]);
        gload16(&Kb [hb + (size_t)r1 * HDD + cl], &Ks[0][(w * 16 + 8) * 64]);
        gload16(&Vtb[hb + (size_t)r0 * SS + cl],  &Vs[0][(w * 16) * 64]);
        gload16(&Vtb[hb + (size_t)r1 * SS + cl],  &Vs[0][(w * 16 + 8) * 64]);
    }

    float lsA = 0.f, lsB = 0.f;
    f32x16 oA0 = {}, oA1 = {}, oB0 = {}, oB1 = {};

    for (int kt = 0; kt < SS / 64; kt++) {
        const int bb = kt & 1;
        if (kt + 1 < SS / 64) {   // issue prefetch, keep it in flight
            const int r0 = w * 16 + l3, r1 = r0 + 8;
            gload16(&Kb [hb + (size_t)((kt + 1) * 64 + r0) * HDD + cl],
                    &Ks[bb ^ 1][(w * 16) * 64]);
            gload16(&Kb [hb + (size_t)((kt + 1) * 64 + r1) * HDD + cl],
                    &Ks[bb ^ 1][(w * 16 + 8) * 64]);
            gload16(&Vtb[hb + (size_t)r0 * SS + (kt + 1) * 64 + cl],
                    &Vs[bb ^ 1][(w * 16) * 64]);
            gload16(&Vtb[hb + (size_t)r1 * SS + (kt + 1) * 64 + cl],
                    &Vs[bb ^ 1][(w * 16 + 8) * 64]);
            WAITV4();   // tile kt's 4 loads done; kt+1's 4 stay in flight
        } else {
            WAITV0();
        }
        SBAR();
        SCHEDB();

        // ---- QK half 0: K rows 0..31, both q-groups share kf.
        f32x16 sA0 = {}, sB0 = {};
        __builtin_amdgcn_s_setprio(1);
        #pragma unroll
        for (int ds = 0; ds < 4; ds++) {
            const int ph = ((ds * 2 + hi) ^ c7) * 8;
            bf16x8 kf = *(const bf16x8*)&Ks[bb][q32 * 64 + ph];
            sA0 = __builtin_amdgcn_mfma_f32_32x32x16_bf16(kf, qfA[ds], sA0, 0, 0, 0);
            sB0 = __builtin_amdgcn_mfma_f32_32x32x16_bf16(kf, qfB[ds], sB0, 0, 0, 0);
        }
        // ---- QK half 1: K rows 32..63.
        f32x16 sA1 = {}, sB1 = {};
        #pragma unroll
        for (int ds = 0; ds < 4; ds++) {
            const int ph = ((ds * 2 + hi) ^ c7) * 8;
            bf16x8 kf = *(const bf16x8*)&Ks[bb][(32 + q32) * 64 + ph];
            sA1 = __builtin_amdgcn_mfma_f32_32x32x16_bf16(kf, qfA[ds], sA1, 0, 0, 0);
            sB1 = __builtin_amdgcn_mfma_f32_32x32x16_bf16(kf, qfB[ds], sB1, 0, 0, 0);
        }
        __builtin_amdgcn_s_setprio(0);

        // ---- pack half 0 (overlaps half-1 MFMAs in the pipe).
        PU paA[4], paB[4];
        packHalf(sA0, &paA[0], lsA);
        packHalf(sB0, &paB[0], lsB);

        // ---- PV k-steps 0,1 (kv 0..31) — needs only pack half 0.
        __builtin_amdgcn_s_setprio(1);
        #pragma unroll
        for (int ks = 0; ks < 2; ks++) {
            const int ph = ((ks * 2 + hi) ^ c7) * 8;
            bf16x8 vf0 = *(const bf16x8*)&Vs[bb][q32 * 64 + ph];
            bf16x8 vf1 = *(const bf16x8*)&Vs[bb][(32 + q32) * 64 + ph];
            oA0 = __builtin_amdgcn_mfma_f32_32x32x16_bf16(paA[ks].v, vf0, oA0, 0, 0, 0);
            oA1 = __builtin_amdgcn_mfma_f32_32x32x16_bf16(paA[ks].v, vf1, oA1, 0, 0, 0);
            oB0 = __builtin_amdgcn_mfma_f32_32x32x16_bf16(paB[ks].v, vf0, oB0, 0, 0, 0);
            oB1 = __builtin_amdgcn_mfma_f32_32x32x16_bf16(paB[ks].v, vf1, oB1, 0, 0, 0);
        }
        __builtin_amdgcn_s_setprio(0);

        // ---- pack half 1 (overlaps PV01 MFMAs).
        packHalf(sA1, &paA[2], lsA);
        packHalf(sB1, &paB[2], lsB);

        // ---- PV k-steps 2,3 (kv 32..63).
        __builtin_amdgcn_s_setprio(1);
        #pragma unroll
        for (int ks = 2; ks < 4; ks++) {
            const int ph = ((ks * 2 + hi) ^ c7) * 8;
            bf16x8 vf0 = *(const bf16x8*)&Vs[bb][q32 * 64 + ph];
            bf16x8 vf1 = *(const bf16x8*)&Vs[bb][(32 + q32) * 64 + ph];
            oA0 = __builtin_amdgcn_mfma_f32_32x32x16_bf16(paA[ks].v, vf0, oA0, 0, 0, 0);
            oA1 = __builtin_amdgcn_mfma_f32_32x32x16_bf16(paA[ks].v, vf1, oA1, 0, 0, 0);
            oB0 = __builtin_amdgcn_mfma_f32_32x32x16_bf16(paB[ks].v, vf0, oB0, 0, 0, 0);
            oB1 = __builtin_amdgcn_mfma_f32_32x32x16_bf16(paB[ks].v, vf1, oB1, 0, 0, 0);
        }
        __builtin_amdgcn_s_setprio(0);

        SCHEDB();
        SBAR();   // all waves done reading buf bb (restaged at kt+2)
    }

    // ---- finalize l: q's row-sum is split across lanes q32 and q32+32.
    lsA += __shfl_xor(lsA, 32);
    lsB += __shfl_xor(lsB, 32);
    const float invA = 1.0f / lsA, invB = 1.0f / lsB;

    // oc rows are q = (r&3)+8*(r>>2)+4*hi; inv lives at lane q (lo half ok).
    #pragma unroll
    for (int r = 0; r < 16; r++) {
        const int cr = (r & 3) + 8 * (r >> 2) + 4 * hi;
        const float iA = __shfl(invA, cr);
        const float iB = __shfl(invB, cr);
        const int rqA = qt * 256 + w * 64 + cr;
        float* oA = &Out[((size_t)(b * SS + rqA)) * HH + h * HDD + q32];
        oA[0]  = oA0[r] * iA;
        oA[32] = oA1[r] * iA;
        float* oB = &Out[((size_t)(b * SS + rqA + 32)) * HH + h * HDD + q32];
        oB[0]  = oB0[r] * iB;
        oB[32] = oB1[r] * iB;
    }
}

// ---------------------------------------------------------------------------
extern "C" void kernel_launch(void* const* d_in, const int* in_sizes, int n_in,
                              void* d_out, int out_size, void* d_ws, size_t ws_size,
                              hipStream_t stream) {
    const float* X  = (const float*)d_in[0];
    const float* Wq = (const float*)d_in[1];
    const float* bq = (const float*)d_in[2];
    const float* Wk = (const float*)d_in[3];
    const float* bk = (const float*)d_in[4];
    const float* Wv = (const float*)d_in[5];
    const float* bv = (const float*)d_in[6];
    float* Out = (float*)d_out;

    const size_t elems = (size_t)BB * SS * HH;  // 8,388,608
    u16* Qw = (u16*)d_ws;                        // Q (pre-scaled) [b,h,s,d]
    u16* Kw = Qw + elems;                        // K [b,h,s,d]
    u16* Vw = Kw + elems;                        // V^T [b,h,d,s]
    // Xb/Wt scratch in d_out (23.1 MB < 33.5 MB; attn fully overwrites).
    u16* Xb = (u16*)d_out;
    u16* Wt = Xb + elems;

    conv<<<dim3(4096 + 3072), 256, 0, stream>>>(X, Wq, Wk, Wv, Xb, Wt);
    qkv_gemm<<<dim3(64, 8, 3), 256, 0, stream>>>(Xb, Wt, bq, bk, bv, Qw, Kw, Vw);
    attn<<<dim3(512), 256, 0, stream>>>(Qw, Kw, Vw, Out);
}